// Round 11
// baseline (756.575 us; speedup 1.0000x reference)
//
#include <hip/hip_runtime.h>
#include <hip/hip_fp16.h>
#include <hip/hip_cooperative_groups.h>

namespace cg = cooperative_groups;

#define N_NODES 100000
#define E_EDGES 1600000
#define F_IN    256
#define F_HID   64
#define F_OUT   16
#define NBKT    391           // buckets of 256 dst-nodes (99999>>8 = 390)
#define CAP     4608          // region size per bucket (mean 4092, +8 sigma)
#define GEMM1_BLOCKS 782      // ceil(N/128): 128-row tiles (round-7-proven)
#define PA_BLOCKS    782      // 2048 edges each (round-7-proven)

typedef _Float16 half8   __attribute__((ext_vector_type(8)));
typedef _Float16 half2v  __attribute__((ext_vector_type(2)));
typedef float    floatx4 __attribute__((ext_vector_type(4)));

// ---------------------------------------------------------------------------
// ONE cooperative kernel, 5 phases separated by grid.sync(). Rationale:
// per-dispatch overhead measured ~12-18 us (round 3->4 merge saved 11 us;
// every round's phase-sum leaves ~90 us unaccounted across 5 dispatches).
// Phase bodies are the round-7/10 proven versions, made grid-stride.
// Atomics and MFMA stay in separate BLOCKS within phase 1 (round-1 lesson:
// same-wave fusion poisons vmcnt waits). deg atomics on 100K words remain
// banned (round-9: +54 MB write traffic from cross-XCD line bounce).
// ---------------------------------------------------------------------------
__global__ __launch_bounds__(256, 8) void mega_kernel(
        const float* __restrict__ x,
        const int* __restrict__ esrc,
        const int* __restrict__ edst,
        const float* __restrict__ evals,
        const float* __restrict__ W1,
        const float* __restrict__ b1,
        const float* __restrict__ W2,
        const float* __restrict__ b2,
        float* __restrict__ out,
        _Float16* __restrict__ support1,
        _Float16* __restrict__ support2,
        int2* __restrict__ tmp,
        int2* __restrict__ sorted_edges,
        int2* __restrict__ rowdeg,
        int* __restrict__ bucketCursor,
        _Float16* __restrict__ W1h) {
    __shared__ __align__(16) char lds[5632];
    const int t = threadIdx.x;
    const int nblk = gridDim.x;
    cg::grid_group grid = cg::this_grid();

    // ================= phase 0: prep (W1h frag-order + cursor zero) ========
    for (int i = blockIdx.x * 256 + t; i < 16384; i += nblk * 256) {
        if (i < NBKT) bucketCursor[i] = 0;
        const int k = i >> 6, n = i & 63;
        const int kb = k >> 5, quad = (k >> 3) & 3, j = k & 7;
        const int nt = n >> 4, ln = n & 15;
        W1h[((kb * 4 + nt) * 64 + quad * 16 + ln) * 8 + j] = (_Float16)W1[i];
    }
    grid.sync();

    // ================= phase 1: gemm1 (MFMA) + passA (bucket scatter) ======
    for (int vb = blockIdx.x; vb < GEMM1_BLOCKS + PA_BLOCKS; vb += nblk) {
        if (vb >= GEMM1_BLOCKS) {
            // ---- passA: 2048 edges ----
            int* hist = (int*)lds;          // NBKT ints
            int* base = hist + NBKT;        // NBKT ints
            const int blk = vb - GEMM1_BLOCKS;
            for (int i = t; i < NBKT; i += 256) hist[i] = 0;
            __syncthreads();
            const int base_e = blk * 2048;
            int rks[2][4];
#pragma unroll
            for (int ch = 0; ch < 2; ++ch) {
                const int e0 = base_e + ch * 1024 + t * 4;
                if (e0 < E_EDGES) {
                    int4 d4 = *(const int4*)&edst[e0];
                    rks[ch][0] = atomicAdd(&hist[d4.x >> 8], 1);
                    rks[ch][1] = atomicAdd(&hist[d4.y >> 8], 1);
                    rks[ch][2] = atomicAdd(&hist[d4.z >> 8], 1);
                    rks[ch][3] = atomicAdd(&hist[d4.w >> 8], 1);
                }
            }
            __syncthreads();
            for (int i = t; i < NBKT; i += 256) {
                const int h = hist[i];
                if (h) base[i] = atomicAdd(&bucketCursor[i], h);
            }
            __syncthreads();
#pragma unroll
            for (int ch = 0; ch < 2; ++ch) {
                const int e0 = base_e + ch * 1024 + t * 4;
                if (e0 < E_EDGES) {
                    int4 d4 = *(const int4*)&edst[e0];    // L1-hot reload
                    int4 s4 = *(const int4*)&esrc[e0];
                    float4 v4 = *(const float4*)&evals[e0];
                    const int dd[4] = {d4.x, d4.y, d4.z, d4.w};
                    const int ss[4] = {s4.x, s4.y, s4.z, s4.w};
                    const float vv[4] = {v4.x, v4.y, v4.z, v4.w};
#pragma unroll
                    for (int u = 0; u < 4; ++u) {
                        const int bu = dd[u] >> 8;
                        const int bpos = base[bu] + rks[ch][u];
                        if (bpos < CAP)   // 8-sigma guard, never hit
                            tmp[(size_t)bu * CAP + bpos] =
                                make_int2(((dd[u] & 255) << 17) | ss[u],
                                          __float_as_int(vv[u]));
                    }
                }
            }
            __syncthreads();   // protect hist/base reuse if loop repeats
        } else {
            // ---- gemm1: 128-row tile, B-frags direct from W1h (L2-hot) ----
            const int wave = t >> 6;
            const int lane = t & 63;
            const int ln   = lane & 15;
            const int quad = lane >> 4;
            const int row0 = vb * 128 + wave * 32;

            const float* xp[2];
#pragma unroll
            for (int mt = 0; mt < 2; ++mt) {
                int r = row0 + mt * 16 + ln;
                if (r > N_NODES - 1) r = N_NODES - 1;
                xp[mt] = x + (size_t)r * F_IN + quad * 8;
            }

            floatx4 acc[2][4] = {};

#pragma unroll 4
            for (int kb = 0; kb < 8; ++kb) {
                half8 a[2];
#pragma unroll
                for (int mt = 0; mt < 2; ++mt) {
                    float4 v0 = *(const float4*)(xp[mt] + kb * 32);
                    float4 v1 = *(const float4*)(xp[mt] + kb * 32 + 4);
                    half8 h;
                    h[0] = (_Float16)v0.x; h[1] = (_Float16)v0.y;
                    h[2] = (_Float16)v0.z; h[3] = (_Float16)v0.w;
                    h[4] = (_Float16)v1.x; h[5] = (_Float16)v1.y;
                    h[6] = (_Float16)v1.z; h[7] = (_Float16)v1.w;
                    a[mt] = h;
                }
#pragma unroll
                for (int nt = 0; nt < 4; ++nt) {
                    half8 bb = *(const half8*)&W1h[((size_t)((kb * 4 + nt) * 64 + lane)) * 8];
                    acc[0][nt] = __builtin_amdgcn_mfma_f32_16x16x32_f16(a[0], bb, acc[0][nt], 0, 0, 0);
                    acc[1][nt] = __builtin_amdgcn_mfma_f32_16x16x32_f16(a[1], bb, acc[1][nt], 0, 0, 0);
                }
            }

#pragma unroll
            for (int mt = 0; mt < 2; ++mt) {
                const int rbase = row0 + mt * 16 + quad * 4;
#pragma unroll
                for (int r = 0; r < 4; ++r) {
                    const int row = rbase + r;
                    if (row < N_NODES) {
#pragma unroll
                        for (int nt = 0; nt < 4; ++nt)
                            support1[(size_t)row * F_HID + nt * 16 + ln] = (_Float16)acc[mt][nt][r];
                    }
                }
            }
        }
    }
    grid.sync();

    // ================= phase 2: passB (two-pass, round-7-proven) ===========
    {
        int* ldeg = (int*)lds;
        int* lcur = ldeg + 256;
        int* s    = lcur + 256;
        for (int b = blockIdx.x; b < NBKT; b += nblk) {
            const int beg = b * CAP;
            int cnt = bucketCursor[b];
            if (cnt > CAP) cnt = CAP;

            ldeg[t] = 0;
            __syncthreads();

            for (int p = t; p < cnt; p += 256) {
                int2 r = tmp[beg + p];
                atomicAdd(&ldeg[r.x >> 17], 1);
            }
            __syncthreads();

            const int v = ldeg[t];
            s[t] = v;
            __syncthreads();
#pragma unroll
            for (int off = 1; off < 256; off <<= 1) {
                const int y = (t >= off) ? s[t - off] : 0;
                __syncthreads();
                s[t] += y;
                __syncthreads();
            }
            const int run = s[t] - v;   // exclusive prefix
            lcur[t] = run;
            const int node = b * 256 + t;
            if (node < N_NODES) rowdeg[node] = make_int2(beg + run, v);
            __syncthreads();

            for (int p = t; p < cnt; p += 256) {
                int2 r = tmp[beg + p];
                const int pos = beg + atomicAdd(&lcur[r.x >> 17], 1);
                sorted_edges[pos] = make_int2(r.x & 0x1FFFF, r.y);
            }
            __syncthreads();   // protect LDS reuse across loop iterations
        }
    }
    grid.sync();

    // ================= phase 3: spmm1 + relu + h@W2 ========================
    {
        float* W2s = (float*)lds;            // 64*17 floats, padded stride
        float* b1s = (float*)(lds + 4352);   // 64 floats
        float* hs  = (float*)(lds + 4608);   // 4 waves * 64 floats
        for (int i = t; i < 1024; i += 256)
            W2s[(i >> 4) * 17 + (i & 15)] = W2[i];
        if (t < 64) b1s[t] = b1[t];
        __syncthreads();

        const int wave = t >> 6;
        const int lane = t & 63;
        const int c4 = lane & 15;             // feature quad
        const int q  = lane >> 4;             // edge parity 0..3
        const int ln   = lane & 15;
        const int quad = lane >> 4;

        for (int g = blockIdx.x; g < 25000; g += nblk) {
            const int node = g * 4 + wave;
            const int2 rd = rowdeg[node];
            const int beg = rd.x;
            const int cnt = rd.y;

            int   src_l = 0;
            float val_l = 0.f;
            if (lane < cnt) {
                int2 ev = sorted_edges[beg + lane];
                src_l = ev.x;
                val_l = __int_as_float(ev.y);
            }

            half2v a01 = {(_Float16)0, (_Float16)0};
            half2v a23 = {(_Float16)0, (_Float16)0};
            const int kmax  = cnt < 64 ? cnt : 64;
            const int quads = (kmax + 3) >> 2;
            const int qp    = (quads + 3) & ~3;   // pad: w=0 slots no-ops
            for (int k = 0; k < qp; k += 4) {
                float w[4]; uint2 d[4];
#pragma unroll
                for (int u = 0; u < 4; ++u) {
                    const int idx = 4 * (k + u) + q;  // <= 63
                    const int s2  = __shfl(src_l, idx);
                    w[u] = __shfl(val_l, idx);
                    d[u] = *(const uint2*)&support1[(s2 << 6) + 4 * c4];
                }
#pragma unroll
                for (int u = 0; u < 4; ++u) {
                    const half2v* hp = (const half2v*)&d[u];
                    const _Float16 wh = (_Float16)w[u];
                    const half2v w2 = {wh, wh};
                    a01 += w2 * hp[0];
                    a23 += w2 * hp[1];
                }
            }
            for (int k = 64 + q; k < cnt; k += 4) {   // rare tail
                int2 ev = sorted_edges[beg + k];
                const uint2 d = *(const uint2*)&support1[(ev.x << 6) + 4 * c4];
                const half2v* hp = (const half2v*)&d;
                const _Float16 wh = (_Float16)__int_as_float(ev.y);
                const half2v w2 = {wh, wh};
                a01 += w2 * hp[0];
                a23 += w2 * hp[1];
            }

            float acc0 = (float)a01[0], acc1 = (float)a01[1];
            float acc2 = (float)a23[0], acc3 = (float)a23[1];
            acc0 += __shfl_xor(acc0, 16); acc0 += __shfl_xor(acc0, 32);
            acc1 += __shfl_xor(acc1, 16); acc1 += __shfl_xor(acc1, 32);
            acc2 += __shfl_xor(acc2, 16); acc2 += __shfl_xor(acc2, 32);
            acc3 += __shfl_xor(acc3, 16); acc3 += __shfl_xor(acc3, 32);
            if (q == 0) {
                float4 hv;
                hv.x = fmaxf(acc0 + b1s[4 * c4],     0.f);
                hv.y = fmaxf(acc1 + b1s[4 * c4 + 1], 0.f);
                hv.z = fmaxf(acc2 + b1s[4 * c4 + 2], 0.f);
                hv.w = fmaxf(acc3 + b1s[4 * c4 + 3], 0.f);
                *(float4*)&hs[wave * 64 + 4 * c4] = hv;
            }
            // hs is strictly per-wave: wave-internal lgkmcnt ordering suffices

            float o = 0.f;
#pragma unroll
            for (int kk = 0; kk < 16; ++kk) {
                const int k2 = quad * 16 + kk;
                o = fmaf(hs[wave * 64 + k2], W2s[k2 * 17 + ln], o);
            }
            o += __shfl_xor(o, 16);
            o += __shfl_xor(o, 32);
            if (quad == 0)
                support2[(size_t)node * F_OUT + ln] = (_Float16)o;
        }
    }
    grid.sync();

    // ================= phase 4: spmm2 + bias + log_softmax =================
    {
        float* b2s = (float*)lds;
        if (t < 16) b2s[t] = b2[t];
        __syncthreads();

        const int j = t & 15;
        const int c = j & 3;
        const int p = j >> 2;

        for (int g = blockIdx.x; g < 6250; g += nblk) {
            const int node = g * 16 + (t >> 4);
            const int2 rd = rowdeg[node];
            const int beg = rd.x;
            const int cnt = rd.y;

            int   src_a = 0, src_b = 0;
            float val_a = 0.f, val_b = 0.f;
            if (j < cnt)      { int2 ev = sorted_edges[beg + j];      src_a = ev.x; val_a = __int_as_float(ev.y); }
            if (j + 16 < cnt) { int2 ev = sorted_edges[beg + 16 + j]; src_b = ev.x; val_b = __int_as_float(ev.y); }

            half2v a01 = {(_Float16)0, (_Float16)0};
            half2v a23 = {(_Float16)0, (_Float16)0};
            {   // batch 1: edges 0..15
                float w[4]; uint2 d[4];
#pragma unroll
                for (int u = 0; u < 4; ++u) {
                    const int idx = 4 * u + p;
                    const int s2  = __shfl(src_a, idx, 16);
                    w[u] = __shfl(val_a, idx, 16);
                    d[u] = *(const uint2*)&support2[(s2 << 4) + 4 * c];
                }
#pragma unroll
                for (int u = 0; u < 4; ++u) {
                    const half2v* hp = (const half2v*)&d[u];
                    const _Float16 wh = (_Float16)w[u];
                    const half2v w2 = {wh, wh};
                    a01 += w2 * hp[0];
                    a23 += w2 * hp[1];
                }
            }
            if (cnt > 16) {   // batch 2: edges 16..31
                float w[4]; uint2 d[4];
#pragma unroll
                for (int u = 0; u < 4; ++u) {
                    const int idx = 4 * u + p;
                    const int s2  = __shfl(src_b, idx, 16);
                    w[u] = __shfl(val_b, idx, 16);
                    d[u] = *(const uint2*)&support2[(s2 << 4) + 4 * c];
                }
#pragma unroll
                for (int u = 0; u < 4; ++u) {
                    const half2v* hp = (const half2v*)&d[u];
                    const _Float16 wh = (_Float16)w[u];
                    const half2v w2 = {wh, wh};
                    a01 += w2 * hp[0];
                    a23 += w2 * hp[1];
                }
            }
            for (int k = 32 + p; k < cnt; k += 4) {   // rare tail
                int2 ev = sorted_edges[beg + k];
                const uint2 d = *(const uint2*)&support2[(ev.x << 4) + 4 * c];
                const half2v* hp = (const half2v*)&d;
                const _Float16 wh = (_Float16)__int_as_float(ev.y);
                const half2v w2 = {wh, wh};
                a01 += w2 * hp[0];
                a23 += w2 * hp[1];
            }

            float acc0 = (float)a01[0], acc1 = (float)a01[1];
            float acc2 = (float)a23[0], acc3 = (float)a23[1];
            acc0 += __shfl_xor(acc0, 4, 16); acc0 += __shfl_xor(acc0, 8, 16);
            acc1 += __shfl_xor(acc1, 4, 16); acc1 += __shfl_xor(acc1, 8, 16);
            acc2 += __shfl_xor(acc2, 4, 16); acc2 += __shfl_xor(acc2, 8, 16);
            acc3 += __shfl_xor(acc3, 4, 16); acc3 += __shfl_xor(acc3, 8, 16);

            const float v0 = acc0 + b2s[4 * c];
            const float v1 = acc1 + b2s[4 * c + 1];
            const float v2 = acc2 + b2s[4 * c + 2];
            const float v3 = acc3 + b2s[4 * c + 3];
            float m = fmaxf(fmaxf(v0, v1), fmaxf(v2, v3));
            m = fmaxf(m, __shfl_xor(m, 1, 16));
            m = fmaxf(m, __shfl_xor(m, 2, 16));
            float sum = __expf(v0 - m) + __expf(v1 - m) + __expf(v2 - m) + __expf(v3 - m);
            sum += __shfl_xor(sum, 1, 16);
            sum += __shfl_xor(sum, 2, 16);
            if (p == 0) {
                const float lse = m + __logf(sum);
                float4 o = make_float4(v0 - lse, v1 - lse, v2 - lse, v3 - lse);
                *(float4*)&out[(size_t)node * F_OUT + 4 * c] = o;
            }
        }
    }
}

// ---------------------------------------------------------------------------
extern "C" void kernel_launch(void* const* d_in, const int* in_sizes, int n_in,
                              void* d_out, int out_size, void* d_ws, size_t ws_size,
                              hipStream_t stream) {
    const float* x     = (const float*)d_in[0];
    const int*   esrc  = (const int*)  d_in[1];
    const int*   edst  = (const int*)  d_in[2];
    const float* evals = (const float*)d_in[3];
    const float* W1    = (const float*)d_in[4];
    const float* b1    = (const float*)d_in[5];
    const float* W2    = (const float*)d_in[6];
    const float* b2    = (const float*)d_in[7];
    float* out = (float*)d_out;

    // Workspace layout (~45.7 MB); all segments 16 B-aligned.
    char* ws = (char*)d_ws;
    _Float16* support1     = (_Float16*)(ws);              // 12,800,000 B
    _Float16* support2     = (_Float16*)(ws + 12800000);   //  3,200,000 B
    int2*     tmp          = (int2*)    (ws + 16000000);   // 14,413,824 B (NBKT*CAP*8)
    int2*     sorted_edges = (int2*)    (ws + 30413824);   // 14,413,824 B
    int2*     rowdeg       = (int2*)    (ws + 44827648);   //    800,000 B
    int*      bucketCursor = (int*)     (ws + 45627648);   //      1,568 B
    _Float16* W1h          = (_Float16*)(ws + 45629216);   //     32,768 B

    // One-time cooperative grid sizing: guaranteed-co-resident block count.
    static int grid = 0;
    if (grid == 0) {
        int perCU = 0;
        hipOccupancyMaxActiveBlocksPerMultiprocessor(&perCU, mega_kernel, 256, 0);
        if (perCU < 1) perCU = 1;
        int dev = 0;
        hipGetDevice(&dev);
        hipDeviceProp_t prop;
        hipGetDeviceProperties(&prop, dev);
        grid = perCU * prop.multiProcessorCount;
        if (grid > 2048) grid = 2048;
        if (grid < 64) grid = 64;
    }

    void* args[] = {(void*)&x, (void*)&esrc, (void*)&edst, (void*)&evals,
                    (void*)&W1, (void*)&b1, (void*)&W2, (void*)&b2,
                    (void*)&out, (void*)&support1, (void*)&support2,
                    (void*)&tmp, (void*)&sorted_edges, (void*)&rowdeg,
                    (void*)&bucketCursor, (void*)&W1h};
    hipLaunchCooperativeKernel((const void*)mega_kernel, dim3(grid), dim3(256),
                               args, 0, stream);
}

// Round 13
// 276.386 us; speedup vs baseline: 2.7374x; 2.7374x over previous
//
#include <hip/hip_runtime.h>
#include <hip/hip_fp16.h>

#define N_NODES 100000
#define E_EDGES 1600000
#define F_IN    256
#define F_HID   64
#define F_OUT   16
#define NBKT    391           // buckets of 256 dst-nodes (99999>>8 = 390)
#define CAP     4608          // region size per bucket (mean 4092, +8 sigma)
#define GEMM1_BLOCKS 782      // ceil(N/128): 128-row tiles (round-7-proven)
#define PA_BLOCKS    782      // 2048 edges each (round-7-proven)

typedef _Float16 half8   __attribute__((ext_vector_type(8)));
typedef _Float16 half2v  __attribute__((ext_vector_type(2)));
typedef float    floatx4 __attribute__((ext_vector_type(4)));

// ---------------------------------------------------------------------------
// K0: prep — zero bucketCursor + convert W1 fp32 -> f16 in MFMA B-fragment
// order (global 32 KB, L2-hot for all gemm blocks; round-6 win: removed the
// per-block 32 KB LDS stage that capped K1 occupancy).
// ---------------------------------------------------------------------------
__global__ __launch_bounds__(256) void prep_kernel(const float* __restrict__ W1,
                                                   _Float16* __restrict__ W1h,
                                                   int* __restrict__ bucketCursor) {
    const int i = blockIdx.x * 256 + threadIdx.x;   // grid: 64 blocks -> i < 16384
    if (i < NBKT) bucketCursor[i] = 0;
    const int k = i >> 6, n = i & 63;
    const int kb = k >> 5, quad = (k >> 3) & 3, j = k & 7;
    const int nt = n >> 4, ln = n & 15;
    W1h[((kb * 4 + nt) * 64 + quad * 16 + ln) * 8 + j] = (_Float16)W1[i];
}

// ---------------------------------------------------------------------------
// K1 (fused, block-specialized, range-split — round-7 config, the measured
// local optimum: 68-71 us): blocks [0,GEMM1_BLOCKS) run MFMA gemm1
// (support1 = x @ W1h, 128-row tiles); blocks after run passA (bucket
// scatter, 2048 edges). Lessons encoded: NO per-node deg atomics (round-9:
// +54 MB cross-XCD line bounce); atomics ONLY in passA blocks (round-1:
// same-wave fusion with MFMA poisons vmcnt); NO cooperative mega-fusion
// (round-11: grid.sync L2 flush + union regalloc spills -> 3.5x slower).
// ---------------------------------------------------------------------------
__global__ __launch_bounds__(256) void gemm1_passA_kernel(const float* __restrict__ x,
                                                          const _Float16* __restrict__ W1h,
                                                          _Float16* __restrict__ support1,
                                                          const int* __restrict__ esrc,
                                                          const int* __restrict__ edst,
                                                          const float* __restrict__ evals,
                                                          int* __restrict__ bucketCursor,
                                                          int2* __restrict__ tmp) {
    __shared__ int hist[NBKT];
    __shared__ int base[NBKT];
    const int t = threadIdx.x;

    if (blockIdx.x >= GEMM1_BLOCKS) {
        // ---- passA: 2048 edges per block ----
        const int blk = blockIdx.x - GEMM1_BLOCKS;
        for (int i = t; i < NBKT; i += 256) hist[i] = 0;
        __syncthreads();
        const int base_e = blk * 2048;
        int rks[2][4];
#pragma unroll
        for (int ch = 0; ch < 2; ++ch) {
            const int e0 = base_e + ch * 1024 + t * 4;
            if (e0 < E_EDGES) {
                int4 d4 = *(const int4*)&edst[e0];
                rks[ch][0] = atomicAdd(&hist[d4.x >> 8], 1);
                rks[ch][1] = atomicAdd(&hist[d4.y >> 8], 1);
                rks[ch][2] = atomicAdd(&hist[d4.z >> 8], 1);
                rks[ch][3] = atomicAdd(&hist[d4.w >> 8], 1);
            }
        }
        __syncthreads();
        for (int i = t; i < NBKT; i += 256) {
            const int h = hist[i];
            if (h) base[i] = atomicAdd(&bucketCursor[i], h);
        }
        __syncthreads();
#pragma unroll
        for (int ch = 0; ch < 2; ++ch) {
            const int e0 = base_e + ch * 1024 + t * 4;
            if (e0 < E_EDGES) {
                int4 d4 = *(const int4*)&edst[e0];    // L1-hot reload
                int4 s4 = *(const int4*)&esrc[e0];
                float4 v4 = *(const float4*)&evals[e0];
                const int dd[4] = {d4.x, d4.y, d4.z, d4.w};
                const int ss[4] = {s4.x, s4.y, s4.z, s4.w};
                const float vv[4] = {v4.x, v4.y, v4.z, v4.w};
#pragma unroll
                for (int u = 0; u < 4; ++u) {
                    const int bu = dd[u] >> 8;
                    const int bpos = base[bu] + rks[ch][u];
                    if (bpos < CAP)   // 8-sigma safety clamp, never hit
                        tmp[(size_t)bu * CAP + bpos] =
                            make_int2(((dd[u] & 255) << 17) | ss[u],
                                      __float_as_int(vv[u]));
                }
            }
        }
        return;
    }

    // ---- MFMA gemm1: B-frags direct from W1h (global, L2-hot) ----
    const int wave = t >> 6;
    const int lane = t & 63;
    const int ln   = lane & 15;
    const int quad = lane >> 4;
    const int row0 = blockIdx.x * 128 + wave * 32;

    const float* xp[2];
#pragma unroll
    for (int mt = 0; mt < 2; ++mt) {
        int r = row0 + mt * 16 + ln;
        if (r > N_NODES - 1) r = N_NODES - 1;
        xp[mt] = x + (size_t)r * F_IN + quad * 8;
    }

    floatx4 acc[2][4] = {};

#pragma unroll 4
    for (int kb = 0; kb < 8; ++kb) {
        half8 a[2];
#pragma unroll
        for (int mt = 0; mt < 2; ++mt) {
            float4 v0 = *(const float4*)(xp[mt] + kb * 32);
            float4 v1 = *(const float4*)(xp[mt] + kb * 32 + 4);
            half8 h;
            h[0] = (_Float16)v0.x; h[1] = (_Float16)v0.y;
            h[2] = (_Float16)v0.z; h[3] = (_Float16)v0.w;
            h[4] = (_Float16)v1.x; h[5] = (_Float16)v1.y;
            h[6] = (_Float16)v1.z; h[7] = (_Float16)v1.w;
            a[mt] = h;
        }
#pragma unroll
        for (int nt = 0; nt < 4; ++nt) {
            half8 b = *(const half8*)&W1h[((size_t)((kb * 4 + nt) * 64 + lane)) * 8];
            acc[0][nt] = __builtin_amdgcn_mfma_f32_16x16x32_f16(a[0], b, acc[0][nt], 0, 0, 0);
            acc[1][nt] = __builtin_amdgcn_mfma_f32_16x16x32_f16(a[1], b, acc[1][nt], 0, 0, 0);
        }
    }

#pragma unroll
    for (int mt = 0; mt < 2; ++mt) {
        const int rbase = row0 + mt * 16 + quad * 4;
#pragma unroll
        for (int r = 0; r < 4; ++r) {
            const int row = rbase + r;
            if (row < N_NODES) {
#pragma unroll
                for (int nt = 0; nt < 4; ++nt)
                    support1[(size_t)row * F_HID + nt * 16 + ln] = (_Float16)acc[mt][nt][r];
            }
        }
    }
}

// ---------------------------------------------------------------------------
// K2: passB — one block per 256-node bucket (391 blocks). REGISTER-RANK
// single-read version (round-10): the count pass captures each edge's rank
// from the LDS histogram atomic and keeps the edge in registers (<=18 int2
// + rank per thread, fully unrolled -> no scratch). After the scan, scatter
// straight from registers.
// ---------------------------------------------------------------------------
__global__ __launch_bounds__(256) void passB_kernel(const int2* __restrict__ tmp,
                                                    const int* __restrict__ bucketCursor,
                                                    int2* __restrict__ sorted_edges,
                                                    int2* __restrict__ rowdeg) {
    __shared__ int ldeg[256];
    __shared__ int lrun[256];
    __shared__ int s[256];
    const int t = threadIdx.x;
    const int b = blockIdx.x;
    const int beg = b * CAP;
    int cnt = bucketCursor[b];
    if (cnt > CAP) cnt = CAP;

    ldeg[t] = 0;
    __syncthreads();

    int2 ev[18];        // CAP/256 = 18 slots max; unrolled -> stays in VGPRs
    int  rk[18];
#pragma unroll
    for (int it = 0; it < 18; ++it) {
        const int p = t + (it << 8);
        if (p < cnt) {
            ev[it] = tmp[beg + p];
            rk[it] = atomicAdd(&ldeg[ev[it].x >> 17], 1);
        }
    }
    __syncthreads();

    const int v = ldeg[t];
    s[t] = v;
    __syncthreads();
#pragma unroll
    for (int off = 1; off < 256; off <<= 1) {
        const int y = (t >= off) ? s[t - off] : 0;
        __syncthreads();
        s[t] += y;
        __syncthreads();
    }
    const int run = s[t] - v;   // exclusive prefix
    lrun[t] = run;
    const int node = b * 256 + t;
    if (node < N_NODES) rowdeg[node] = make_int2(beg + run, v);
    __syncthreads();

#pragma unroll
    for (int it = 0; it < 18; ++it) {
        const int p = t + (it << 8);
        if (p < cnt) {
            const int nl = ev[it].x >> 17;
            sorted_edges[beg + lrun[nl] + rk[it]] =
                make_int2(ev[it].x & 0x1FFFF, ev[it].y);
        }
    }
}

// ---------------------------------------------------------------------------
// K3 fused: h = relu(spmm(support1) + b1); support2 = h @ W2 (f16 out).
// 16 nodes per block (4 per wave, fully unrolled): W2s/b1s staging
// amortized 4x; rowdeg + all 4 edge-preloads issued upfront so node n+1's
// latency overlaps node n's fma/reduce. Gather core unchanged (round-3
// quad-gather + round-7 pk-fma + 32-bit addressing).
// ROUND-12 BUGFIX: the hs store->read ordering needs explicit barriers —
// the predicated float4 LDS store followed by unconditional float loads is
// NOT ordered by the compiler without them (absmax 30.75 failure). Barriers
// are uniform (fixed 4-iteration loop, exact grid), cost ~1 us total.
// ---------------------------------------------------------------------------
__global__ __launch_bounds__(256) void spmm1_fused_kernel(const int2* __restrict__ rowdeg,
                                                          const int2* __restrict__ sorted_edges,
                                                          const _Float16* __restrict__ support1,
                                                          const float* __restrict__ b1,
                                                          const float* __restrict__ W2,
                                                          _Float16* __restrict__ support2) {
    __shared__ float W2s[64 * 17];   // padded stride 17
    __shared__ float b1s[64];
    __shared__ __align__(16) float hs[4][64];
    const int t = threadIdx.x;
    for (int i = t; i < 1024; i += 256)
        W2s[(i >> 4) * 17 + (i & 15)] = W2[i];
    if (t < 64) b1s[t] = b1[t];
    __syncthreads();

    const int wave = t >> 6;
    const int lane = t & 63;
    const int c4 = lane & 15;                 // feature quad
    const int q  = lane >> 4;                 // edge parity 0..3
    const int ln   = lane & 15;
    const int quad = lane >> 4;
    const int node0 = blockIdx.x * 16 + wave * 4;   // grid exact: 6250*16

    // upfront: rowdeg + edge preloads for all 4 nodes (independent loads)
    int2 rd[4];
#pragma unroll
    for (int nn = 0; nn < 4; ++nn) rd[nn] = rowdeg[node0 + nn];

    int   src_l[4];
    float val_l[4];
#pragma unroll
    for (int nn = 0; nn < 4; ++nn) {
        src_l[nn] = 0; val_l[nn] = 0.f;
        if (lane < rd[nn].y) {
            int2 ev = sorted_edges[rd[nn].x + lane];
            src_l[nn] = ev.x;
            val_l[nn] = __int_as_float(ev.y);
        }
    }

#pragma unroll
    for (int nn = 0; nn < 4; ++nn) {
        const int beg = rd[nn].x;
        const int cnt = rd[nn].y;

        half2v a01 = {(_Float16)0, (_Float16)0};
        half2v a23 = {(_Float16)0, (_Float16)0};
        const int kmax  = cnt < 64 ? cnt : 64;
        const int quads = (kmax + 3) >> 2;
        const int qp    = (quads + 3) & ~3;       // pad: w=0 slots are no-ops
        for (int k = 0; k < qp; k += 4) {
            float w[4]; uint2 d[4];
#pragma unroll
            for (int u = 0; u < 4; ++u) {
                const int idx = 4 * (k + u) + q;  // <= 63
                const int s2  = __shfl(src_l[nn], idx);
                w[u] = __shfl(val_l[nn], idx);
                d[u] = *(const uint2*)&support1[(s2 << 6) + 4 * c4];
            }
#pragma unroll
            for (int u = 0; u < 4; ++u) {
                const half2v* hp = (const half2v*)&d[u];
                const _Float16 wh = (_Float16)w[u];
                const half2v w2 = {wh, wh};
                a01 += w2 * hp[0];
                a23 += w2 * hp[1];
            }
        }
        for (int k = 64 + q; k < cnt; k += 4) {   // rare tail, parity-split
            int2 ev = sorted_edges[beg + k];
            const uint2 d = *(const uint2*)&support1[(ev.x << 6) + 4 * c4];
            const half2v* hp = (const half2v*)&d;
            const _Float16 wh = (_Float16)__int_as_float(ev.y);
            const half2v w2 = {wh, wh};
            a01 += w2 * hp[0];
            a23 += w2 * hp[1];
        }

        float acc0 = (float)a01[0], acc1 = (float)a01[1];
        float acc2 = (float)a23[0], acc3 = (float)a23[1];
        acc0 += __shfl_xor(acc0, 16); acc0 += __shfl_xor(acc0, 32);
        acc1 += __shfl_xor(acc1, 16); acc1 += __shfl_xor(acc1, 32);
        acc2 += __shfl_xor(acc2, 16); acc2 += __shfl_xor(acc2, 32);
        acc3 += __shfl_xor(acc3, 16); acc3 += __shfl_xor(acc3, 32);
        if (q == 0) {
            float4 hv;
            hv.x = fmaxf(acc0 + b1s[4 * c4],     0.f);
            hv.y = fmaxf(acc1 + b1s[4 * c4 + 1], 0.f);
            hv.z = fmaxf(acc2 + b1s[4 * c4 + 2], 0.f);
            hv.w = fmaxf(acc3 + b1s[4 * c4 + 3], 0.f);
            *(float4*)&hs[wave][4 * c4] = hv;
        }
        __syncthreads();   // order hs store -> epilogue reads (round-12 bug)

        float o = 0.f;
#pragma unroll
        for (int kk = 0; kk < 16; ++kk) {
            const int k2 = quad * 16 + kk;
            o = fmaf(hs[wave][k2], W2s[k2 * 17 + ln], o);
        }
        o += __shfl_xor(o, 16);
        o += __shfl_xor(o, 32);
        if (quad == 0)
            support2[(size_t)(node0 + nn) * F_OUT + ln] = (_Float16)o;
        __syncthreads();   // order epilogue reads -> next iteration's store
    }
}

// ---------------------------------------------------------------------------
// K4 fused: logits = spmm(support2) + b2, then log_softmax.
// 64 nodes per block (4 per 16-lane group, unrolled; grid 1563 with uniform
// tail guard). rowdeg preloaded upfront. No per-iteration LDS (no round-12
// hazard here). Gather core unchanged (quad-gather width 16 + pk-fma +
// 32-bit addressing).
// ---------------------------------------------------------------------------
__global__ __launch_bounds__(256) void spmm2_fused_kernel(const int2* __restrict__ rowdeg,
                                                          const int2* __restrict__ sorted_edges,
                                                          const _Float16* __restrict__ support2,
                                                          const float* __restrict__ b2,
                                                          float* __restrict__ out) {
    __shared__ float b2s[16];
    const int t = threadIdx.x;
    if (t < 16) b2s[t] = b2[t];
    __syncthreads();

    const int j = t & 15;
    const int c = j & 3;
    const int p = j >> 2;
    const int node0 = blockIdx.x * 64 + (t >> 4) * 4;   // grid: 1563 (guarded)

    int2 rd[4];
#pragma unroll
    for (int nn = 0; nn < 4; ++nn)
        rd[nn] = (node0 + nn < N_NODES) ? rowdeg[node0 + nn] : make_int2(0, 0);

#pragma unroll
    for (int nn = 0; nn < 4; ++nn) {
        const int node = node0 + nn;
        if (node >= N_NODES) break;   // uniform within 16-lane group
        const int beg = rd[nn].x;
        const int cnt = rd[nn].y;

        int   src_a = 0, src_b = 0;
        float val_a = 0.f, val_b = 0.f;
        if (j < cnt)      { int2 ev = sorted_edges[beg + j];      src_a = ev.x; val_a = __int_as_float(ev.y); }
        if (j + 16 < cnt) { int2 ev = sorted_edges[beg + 16 + j]; src_b = ev.x; val_b = __int_as_float(ev.y); }

        half2v a01 = {(_Float16)0, (_Float16)0};
        half2v a23 = {(_Float16)0, (_Float16)0};
        {   // batch 1: edges 0..15 (4 quad-iters; w=0 beyond cnt)
            float w[4]; uint2 d[4];
#pragma unroll
            for (int u = 0; u < 4; ++u) {
                const int idx = 4 * u + p;
                const int s2  = __shfl(src_a, idx, 16);
                w[u] = __shfl(val_a, idx, 16);
                d[u] = *(const uint2*)&support2[(s2 << 4) + 4 * c];
            }
#pragma unroll
            for (int u = 0; u < 4; ++u) {
                const half2v* hp = (const half2v*)&d[u];
                const _Float16 wh = (_Float16)w[u];
                const half2v w2 = {wh, wh};
                a01 += w2 * hp[0];
                a23 += w2 * hp[1];
            }
        }
        if (cnt > 16) {   // batch 2: edges 16..31
            float w[4]; uint2 d[4];
#pragma unroll
            for (int u = 0; u < 4; ++u) {
                const int idx = 4 * u + p;
                const int s2  = __shfl(src_b, idx, 16);
                w[u] = __shfl(val_b, idx, 16);
                d[u] = *(const uint2*)&support2[(s2 << 4) + 4 * c];
            }
#pragma unroll
            for (int u = 0; u < 4; ++u) {
                const half2v* hp = (const half2v*)&d[u];
                const _Float16 wh = (_Float16)w[u];
                const half2v w2 = {wh, wh};
                a01 += w2 * hp[0];
                a23 += w2 * hp[1];
            }
        }
        for (int k = 32 + p; k < cnt; k += 4) {   // rare tail, parity-split
            int2 ev = sorted_edges[beg + k];
            const uint2 d = *(const uint2*)&support2[(ev.x << 4) + 4 * c];
            const half2v* hp = (const half2v*)&d;
            const _Float16 wh = (_Float16)__int_as_float(ev.y);
            const half2v w2 = {wh, wh};
            a01 += w2 * hp[0];
            a23 += w2 * hp[1];
        }

        float acc0 = (float)a01[0], acc1 = (float)a01[1];
        float acc2 = (float)a23[0], acc3 = (float)a23[1];
        acc0 += __shfl_xor(acc0, 4, 16); acc0 += __shfl_xor(acc0, 8, 16);
        acc1 += __shfl_xor(acc1, 4, 16); acc1 += __shfl_xor(acc1, 8, 16);
        acc2 += __shfl_xor(acc2, 4, 16); acc2 += __shfl_xor(acc2, 8, 16);
        acc3 += __shfl_xor(acc3, 4, 16); acc3 += __shfl_xor(acc3, 8, 16);

        const float v0 = acc0 + b2s[4 * c];
        const float v1 = acc1 + b2s[4 * c + 1];
        const float v2 = acc2 + b2s[4 * c + 2];
        const float v3 = acc3 + b2s[4 * c + 3];
        float m = fmaxf(fmaxf(v0, v1), fmaxf(v2, v3));
        m = fmaxf(m, __shfl_xor(m, 1, 16));
        m = fmaxf(m, __shfl_xor(m, 2, 16));
        float sum = __expf(v0 - m) + __expf(v1 - m) + __expf(v2 - m) + __expf(v3 - m);
        sum += __shfl_xor(sum, 1, 16);
        sum += __shfl_xor(sum, 2, 16);
        if (p == 0) {
            const float lse = m + __logf(sum);
            float4 o = make_float4(v0 - lse, v1 - lse, v2 - lse, v3 - lse);
            *(float4*)&out[(size_t)node * F_OUT + 4 * c] = o;
        }
    }
}

// ---------------------------------------------------------------------------
extern "C" void kernel_launch(void* const* d_in, const int* in_sizes, int n_in,
                              void* d_out, int out_size, void* d_ws, size_t ws_size,
                              hipStream_t stream) {
    const float* x     = (const float*)d_in[0];
    const int*   esrc  = (const int*)  d_in[1];
    const int*   edst  = (const int*)  d_in[2];
    const float* evals = (const float*)d_in[3];
    const float* W1    = (const float*)d_in[4];
    const float* b1    = (const float*)d_in[5];
    const float* W2    = (const float*)d_in[6];
    const float* b2    = (const float*)d_in[7];
    float* out = (float*)d_out;

    // Workspace layout (~45.7 MB); all segments 16 B-aligned.
    char* ws = (char*)d_ws;
    _Float16* support1     = (_Float16*)(ws);              // 12,800,000 B
    _Float16* support2     = (_Float16*)(ws + 12800000);   //  3,200,000 B
    int2*     tmp          = (int2*)    (ws + 16000000);   // 14,413,824 B (NBKT*CAP*8)
    int2*     sorted_edges = (int2*)    (ws + 30413824);   // 14,413,824 B
    int2*     rowdeg       = (int2*)    (ws + 44827648);   //    800,000 B
    int*      bucketCursor = (int*)     (ws + 45627648);   //      1,568 B
    _Float16* W1h          = (_Float16*)(ws + 45629216);   //     32,768 B

    prep_kernel<<<64, 256, 0, stream>>>(W1, W1h, bucketCursor);
    gemm1_passA_kernel<<<GEMM1_BLOCKS + PA_BLOCKS, 256, 0, stream>>>(
        x, W1h, support1, esrc, edst, evals, bucketCursor, tmp);
    passB_kernel<<<NBKT, 256, 0, stream>>>(tmp, bucketCursor, sorted_edges, rowdeg);
    spmm1_fused_kernel<<<N_NODES / 16, 256, 0, stream>>>(rowdeg, sorted_edges,
                                                         support1, b1, W2, support2);
    spmm2_fused_kernel<<<(N_NODES + 63) / 64, 256, 0, stream>>>(rowdeg, sorted_edges,
                                                                support2, b2, out);
}

// Round 14
// 275.410 us; speedup vs baseline: 2.7471x; 1.0035x over previous
//
#include <hip/hip_runtime.h>
#include <hip/hip_fp16.h>

#define N_NODES 100000
#define E_EDGES 1600000
#define F_IN    256
#define F_HID   64
#define F_OUT   16
#define NBKT    391           // buckets of 256 dst-nodes (99999>>8 = 390)
#define CAP     4608          // region size per bucket (mean 4092, +8 sigma)
#define GEMM1_BLOCKS 782      // ceil(N/128): 128-row tiles (round-7-proven)
#define PA_BLOCKS    782      // 2048 edges each (round-7-proven)

typedef _Float16 half8   __attribute__((ext_vector_type(8)));
typedef _Float16 half2v  __attribute__((ext_vector_type(2)));
typedef float    floatx4 __attribute__((ext_vector_type(4)));

// ---------------------------------------------------------------------------
// K0: prep — zero bucketCursor + convert W1 fp32 -> f16 in MFMA B-fragment
// order (global 32 KB, L2-hot for all gemm blocks; round-6 win: removed the
// per-block 32 KB LDS stage that capped K1 occupancy).
// ---------------------------------------------------------------------------
__global__ __launch_bounds__(256) void prep_kernel(const float* __restrict__ W1,
                                                   _Float16* __restrict__ W1h,
                                                   int* __restrict__ bucketCursor) {
    const int i = blockIdx.x * 256 + threadIdx.x;   // grid: 64 blocks -> i < 16384
    if (i < NBKT) bucketCursor[i] = 0;
    const int k = i >> 6, n = i & 63;
    const int kb = k >> 5, quad = (k >> 3) & 3, j = k & 7;
    const int nt = n >> 4, ln = n & 15;
    W1h[((kb * 4 + nt) * 64 + quad * 16 + ln) * 8 + j] = (_Float16)W1[i];
}

// ---------------------------------------------------------------------------
// K1 (fused, block-specialized, range-split — round-7 config, the measured
// local optimum: 68-71 us): blocks [0,GEMM1_BLOCKS) run MFMA gemm1
// (support1 = x @ W1h, 128-row tiles); blocks after run passA (bucket
// scatter, 2048 edges). Lessons encoded: NO per-node deg atomics (round-9:
// +54 MB cross-XCD line bounce); atomics ONLY in passA blocks (round-1:
// same-wave fusion with MFMA poisons vmcnt); NO cooperative mega-fusion
// (round-11: grid.sync L2 flush + union regalloc spills -> 3.5x slower).
// ---------------------------------------------------------------------------
__global__ __launch_bounds__(256) void gemm1_passA_kernel(const float* __restrict__ x,
                                                          const _Float16* __restrict__ W1h,
                                                          _Float16* __restrict__ support1,
                                                          const int* __restrict__ esrc,
                                                          const int* __restrict__ edst,
                                                          const float* __restrict__ evals,
                                                          int* __restrict__ bucketCursor,
                                                          int2* __restrict__ tmp) {
    __shared__ int hist[NBKT];
    __shared__ int base[NBKT];
    const int t = threadIdx.x;

    if (blockIdx.x >= GEMM1_BLOCKS) {
        // ---- passA: 2048 edges per block ----
        const int blk = blockIdx.x - GEMM1_BLOCKS;
        for (int i = t; i < NBKT; i += 256) hist[i] = 0;
        __syncthreads();
        const int base_e = blk * 2048;
        int rks[2][4];
#pragma unroll
        for (int ch = 0; ch < 2; ++ch) {
            const int e0 = base_e + ch * 1024 + t * 4;
            if (e0 < E_EDGES) {
                int4 d4 = *(const int4*)&edst[e0];
                rks[ch][0] = atomicAdd(&hist[d4.x >> 8], 1);
                rks[ch][1] = atomicAdd(&hist[d4.y >> 8], 1);
                rks[ch][2] = atomicAdd(&hist[d4.z >> 8], 1);
                rks[ch][3] = atomicAdd(&hist[d4.w >> 8], 1);
            }
        }
        __syncthreads();
        for (int i = t; i < NBKT; i += 256) {
            const int h = hist[i];
            if (h) base[i] = atomicAdd(&bucketCursor[i], h);
        }
        __syncthreads();
#pragma unroll
        for (int ch = 0; ch < 2; ++ch) {
            const int e0 = base_e + ch * 1024 + t * 4;
            if (e0 < E_EDGES) {
                int4 d4 = *(const int4*)&edst[e0];    // L1-hot reload
                int4 s4 = *(const int4*)&esrc[e0];
                float4 v4 = *(const float4*)&evals[e0];
                const int dd[4] = {d4.x, d4.y, d4.z, d4.w};
                const int ss[4] = {s4.x, s4.y, s4.z, s4.w};
                const float vv[4] = {v4.x, v4.y, v4.z, v4.w};
#pragma unroll
                for (int u = 0; u < 4; ++u) {
                    const int bu = dd[u] >> 8;
                    const int bpos = base[bu] + rks[ch][u];
                    if (bpos < CAP)   // 8-sigma safety clamp, never hit
                        tmp[(size_t)bu * CAP + bpos] =
                            make_int2(((dd[u] & 255) << 17) | ss[u],
                                      __float_as_int(vv[u]));
                }
            }
        }
        return;
    }

    // ---- MFMA gemm1: B-frags direct from W1h (global, L2-hot) ----
    const int wave = t >> 6;
    const int lane = t & 63;
    const int ln   = lane & 15;
    const int quad = lane >> 4;
    const int row0 = blockIdx.x * 128 + wave * 32;

    const float* xp[2];
#pragma unroll
    for (int mt = 0; mt < 2; ++mt) {
        int r = row0 + mt * 16 + ln;
        if (r > N_NODES - 1) r = N_NODES - 1;
        xp[mt] = x + (size_t)r * F_IN + quad * 8;
    }

    floatx4 acc[2][4] = {};

#pragma unroll 4
    for (int kb = 0; kb < 8; ++kb) {
        half8 a[2];
#pragma unroll
        for (int mt = 0; mt < 2; ++mt) {
            float4 v0 = *(const float4*)(xp[mt] + kb * 32);
            float4 v1 = *(const float4*)(xp[mt] + kb * 32 + 4);
            half8 h;
            h[0] = (_Float16)v0.x; h[1] = (_Float16)v0.y;
            h[2] = (_Float16)v0.z; h[3] = (_Float16)v0.w;
            h[4] = (_Float16)v1.x; h[5] = (_Float16)v1.y;
            h[6] = (_Float16)v1.z; h[7] = (_Float16)v1.w;
            a[mt] = h;
        }
#pragma unroll
        for (int nt = 0; nt < 4; ++nt) {
            half8 b = *(const half8*)&W1h[((size_t)((kb * 4 + nt) * 64 + lane)) * 8];
            acc[0][nt] = __builtin_amdgcn_mfma_f32_16x16x32_f16(a[0], b, acc[0][nt], 0, 0, 0);
            acc[1][nt] = __builtin_amdgcn_mfma_f32_16x16x32_f16(a[1], b, acc[1][nt], 0, 0, 0);
        }
    }

#pragma unroll
    for (int mt = 0; mt < 2; ++mt) {
        const int rbase = row0 + mt * 16 + quad * 4;
#pragma unroll
        for (int r = 0; r < 4; ++r) {
            const int row = rbase + r;
            if (row < N_NODES) {
#pragma unroll
                for (int nt = 0; nt < 4; ++nt)
                    support1[(size_t)row * F_HID + nt * 16 + ln] = (_Float16)acc[mt][nt][r];
            }
        }
    }
}

// ---------------------------------------------------------------------------
// K2: passB — one block per 256-node bucket (391 blocks), NOW 1024 THREADS.
// Round-13 budget analysis: passB was the only unprofiled kernel and the
// ~85 us residual points at it; at 256 threads it ran 1.5 blocks/CU = ~6
// waves/CU — the worst occupancy in the pipeline. 1024 threads/block gives
// 16 waves/block (~24 waves/CU resident), 4x the latency hiding for the
// tmp read + LDS-atomic histogram + scatter. Same register-rank single-read
// algorithm (ev[5]/rk[5], fully unrolled -> VGPRs). The 256-bin scan is
// guarded to t<256 with UNIFORM barriers (all 1024 threads reach every
// __syncthreads — no round-12-style divergent-ordering hazard).
// ---------------------------------------------------------------------------
__global__ __launch_bounds__(1024) void passB_kernel(const int2* __restrict__ tmp,
                                                     const int* __restrict__ bucketCursor,
                                                     int2* __restrict__ sorted_edges,
                                                     int2* __restrict__ rowdeg) {
    __shared__ int ldeg[256];
    __shared__ int lrun[256];
    __shared__ int s[256];
    const int t = threadIdx.x;
    const int b = blockIdx.x;
    const int beg = b * CAP;
    int cnt = bucketCursor[b];
    if (cnt > CAP) cnt = CAP;

    if (t < 256) ldeg[t] = 0;
    __syncthreads();

    int2 ev[5];         // ceil(CAP/1024) = 5 slots; unrolled -> stays in VGPRs
    int  rk[5];
#pragma unroll
    for (int it = 0; it < 5; ++it) {
        const int p = t + it * 1024;
        if (p < cnt) {
            ev[it] = tmp[beg + p];
            rk[it] = atomicAdd(&ldeg[ev[it].x >> 17], 1);
        }
    }
    __syncthreads();

    const int v = (t < 256) ? ldeg[t] : 0;
    if (t < 256) s[t] = v;
    __syncthreads();
#pragma unroll
    for (int off = 1; off < 256; off <<= 1) {
        int y = 0;
        if (t < 256 && t >= off) y = s[t - off];
        __syncthreads();
        if (t < 256) s[t] += y;
        __syncthreads();
    }
    if (t < 256) {
        const int run = s[t] - v;   // exclusive prefix
        lrun[t] = run;
        const int node = b * 256 + t;
        if (node < N_NODES) rowdeg[node] = make_int2(beg + run, v);
    }
    __syncthreads();

#pragma unroll
    for (int it = 0; it < 5; ++it) {
        const int p = t + it * 1024;
        if (p < cnt) {
            const int nl = ev[it].x >> 17;
            sorted_edges[beg + lrun[nl] + rk[it]] =
                make_int2(ev[it].x & 0x1FFFF, ev[it].y);
        }
    }
}

// ---------------------------------------------------------------------------
// K3 fused: h = relu(spmm(support1) + b1); support2 = h @ W2 (f16 out).
// 16 nodes per block (4 per wave, fully unrolled): W2s/b1s staging
// amortized 4x; rowdeg + all 4 edge-preloads issued upfront so node n+1's
// latency overlaps node n's fma/reduce. Gather core unchanged (round-3
// quad-gather + round-7 pk-fma + 32-bit addressing). Barriers around the
// hs store->read are REQUIRED (round-12 failure: predicated float4 LDS
// store + unconditional loads are not compiler-ordered without them).
// ---------------------------------------------------------------------------
__global__ __launch_bounds__(256) void spmm1_fused_kernel(const int2* __restrict__ rowdeg,
                                                          const int2* __restrict__ sorted_edges,
                                                          const _Float16* __restrict__ support1,
                                                          const float* __restrict__ b1,
                                                          const float* __restrict__ W2,
                                                          _Float16* __restrict__ support2) {
    __shared__ float W2s[64 * 17];   // padded stride 17
    __shared__ float b1s[64];
    __shared__ __align__(16) float hs[4][64];
    const int t = threadIdx.x;
    for (int i = t; i < 1024; i += 256)
        W2s[(i >> 4) * 17 + (i & 15)] = W2[i];
    if (t < 64) b1s[t] = b1[t];
    __syncthreads();

    const int wave = t >> 6;
    const int lane = t & 63;
    const int c4 = lane & 15;                 // feature quad
    const int q  = lane >> 4;                 // edge parity 0..3
    const int ln   = lane & 15;
    const int quad = lane >> 4;
    const int node0 = blockIdx.x * 16 + wave * 4;   // grid exact: 6250*16

    // upfront: rowdeg + edge preloads for all 4 nodes (independent loads)
    int2 rd[4];
#pragma unroll
    for (int nn = 0; nn < 4; ++nn) rd[nn] = rowdeg[node0 + nn];

    int   src_l[4];
    float val_l[4];
#pragma unroll
    for (int nn = 0; nn < 4; ++nn) {
        src_l[nn] = 0; val_l[nn] = 0.f;
        if (lane < rd[nn].y) {
            int2 ev = sorted_edges[rd[nn].x + lane];
            src_l[nn] = ev.x;
            val_l[nn] = __int_as_float(ev.y);
        }
    }

#pragma unroll
    for (int nn = 0; nn < 4; ++nn) {
        const int beg = rd[nn].x;
        const int cnt = rd[nn].y;

        half2v a01 = {(_Float16)0, (_Float16)0};
        half2v a23 = {(_Float16)0, (_Float16)0};
        const int kmax  = cnt < 64 ? cnt : 64;
        const int quads = (kmax + 3) >> 2;
        const int qp    = (quads + 3) & ~3;       // pad: w=0 slots are no-ops
        for (int k = 0; k < qp; k += 4) {
            float w[4]; uint2 d[4];
#pragma unroll
            for (int u = 0; u < 4; ++u) {
                const int idx = 4 * (k + u) + q;  // <= 63
                const int s2  = __shfl(src_l[nn], idx);
                w[u] = __shfl(val_l[nn], idx);
                d[u] = *(const uint2*)&support1[(s2 << 6) + 4 * c4];
            }
#pragma unroll
            for (int u = 0; u < 4; ++u) {
                const half2v* hp = (const half2v*)&d[u];
                const _Float16 wh = (_Float16)w[u];
                const half2v w2 = {wh, wh};
                a01 += w2 * hp[0];
                a23 += w2 * hp[1];
            }
        }
        for (int k = 64 + q; k < cnt; k += 4) {   // rare tail, parity-split
            int2 ev = sorted_edges[beg + k];
            const uint2 d = *(const uint2*)&support1[(ev.x << 6) + 4 * c4];
            const half2v* hp = (const half2v*)&d;
            const _Float16 wh = (_Float16)__int_as_float(ev.y);
            const half2v w2 = {wh, wh};
            a01 += w2 * hp[0];
            a23 += w2 * hp[1];
        }

        float acc0 = (float)a01[0], acc1 = (float)a01[1];
        float acc2 = (float)a23[0], acc3 = (float)a23[1];
        acc0 += __shfl_xor(acc0, 16); acc0 += __shfl_xor(acc0, 32);
        acc1 += __shfl_xor(acc1, 16); acc1 += __shfl_xor(acc1, 32);
        acc2 += __shfl_xor(acc2, 16); acc2 += __shfl_xor(acc2, 32);
        acc3 += __shfl_xor(acc3, 16); acc3 += __shfl_xor(acc3, 32);
        if (q == 0) {
            float4 hv;
            hv.x = fmaxf(acc0 + b1s[4 * c4],     0.f);
            hv.y = fmaxf(acc1 + b1s[4 * c4 + 1], 0.f);
            hv.z = fmaxf(acc2 + b1s[4 * c4 + 2], 0.f);
            hv.w = fmaxf(acc3 + b1s[4 * c4 + 3], 0.f);
            *(float4*)&hs[wave][4 * c4] = hv;
        }
        __syncthreads();   // order hs store -> epilogue reads (round-12 bug)

        float o = 0.f;
#pragma unroll
        for (int kk = 0; kk < 16; ++kk) {
            const int k2 = quad * 16 + kk;
            o = fmaf(hs[wave][k2], W2s[k2 * 17 + ln], o);
        }
        o += __shfl_xor(o, 16);
        o += __shfl_xor(o, 32);
        if (quad == 0)
            support2[(size_t)(node0 + nn) * F_OUT + ln] = (_Float16)o;
        __syncthreads();   // order epilogue reads -> next iteration's store
    }
}

// ---------------------------------------------------------------------------
// K4 fused: logits = spmm(support2) + b2, then log_softmax.
// 64 nodes per block (4 per 16-lane group, unrolled; grid 1563 with uniform
// tail guard). rowdeg preloaded upfront. No per-iteration LDS. Gather core
// unchanged (quad-gather width 16 + pk-fma + 32-bit addressing).
// ---------------------------------------------------------------------------
__global__ __launch_bounds__(256) void spmm2_fused_kernel(const int2* __restrict__ rowdeg,
                                                          const int2* __restrict__ sorted_edges,
                                                          const _Float16* __restrict__ support2,
                                                          const float* __restrict__ b2,
                                                          float* __restrict__ out) {
    __shared__ float b2s[16];
    const int t = threadIdx.x;
    if (t < 16) b2s[t] = b2[t];
    __syncthreads();

    const int j = t & 15;
    const int c = j & 3;
    const int p = j >> 2;
    const int node0 = blockIdx.x * 64 + (t >> 4) * 4;   // grid: 1563 (guarded)

    int2 rd[4];
#pragma unroll
    for (int nn = 0; nn < 4; ++nn)
        rd[nn] = (node0 + nn < N_NODES) ? rowdeg[node0 + nn] : make_int2(0, 0);

#pragma unroll
    for (int nn = 0; nn < 4; ++nn) {
        const int node = node0 + nn;
        if (node >= N_NODES) break;   // uniform within 16-lane group
        const int beg = rd[nn].x;
        const int cnt = rd[nn].y;

        int   src_a = 0, src_b = 0;
        float val_a = 0.f, val_b = 0.f;
        if (j < cnt)      { int2 ev = sorted_edges[beg + j];      src_a = ev.x; val_a = __int_as_float(ev.y); }
        if (j + 16 < cnt) { int2 ev = sorted_edges[beg + 16 + j]; src_b = ev.x; val_b = __int_as_float(ev.y); }

        half2v a01 = {(_Float16)0, (_Float16)0};
        half2v a23 = {(_Float16)0, (_Float16)0};
        {   // batch 1: edges 0..15 (4 quad-iters; w=0 beyond cnt)
            float w[4]; uint2 d[4];
#pragma unroll
            for (int u = 0; u < 4; ++u) {
                const int idx = 4 * u + p;
                const int s2  = __shfl(src_a, idx, 16);
                w[u] = __shfl(val_a, idx, 16);
                d[u] = *(const uint2*)&support2[(s2 << 4) + 4 * c];
            }
#pragma unroll
            for (int u = 0; u < 4; ++u) {
                const half2v* hp = (const half2v*)&d[u];
                const _Float16 wh = (_Float16)w[u];
                const half2v w2 = {wh, wh};
                a01 += w2 * hp[0];
                a23 += w2 * hp[1];
            }
        }
        if (cnt > 16) {   // batch 2: edges 16..31
            float w[4]; uint2 d[4];
#pragma unroll
            for (int u = 0; u < 4; ++u) {
                const int idx = 4 * u + p;
                const int s2  = __shfl(src_b, idx, 16);
                w[u] = __shfl(val_b, idx, 16);
                d[u] = *(const uint2*)&support2[(s2 << 4) + 4 * c];
            }
#pragma unroll
            for (int u = 0; u < 4; ++u) {
                const half2v* hp = (const half2v*)&d[u];
                const _Float16 wh = (_Float16)w[u];
                const half2v w2 = {wh, wh};
                a01 += w2 * hp[0];
                a23 += w2 * hp[1];
            }
        }
        for (int k = 32 + p; k < cnt; k += 4) {   // rare tail, parity-split
            int2 ev = sorted_edges[beg + k];
            const uint2 d = *(const uint2*)&support2[(ev.x << 4) + 4 * c];
            const half2v* hp = (const half2v*)&d;
            const _Float16 wh = (_Float16)__int_as_float(ev.y);
            const half2v w2 = {wh, wh};
            a01 += w2 * hp[0];
            a23 += w2 * hp[1];
        }

        float acc0 = (float)a01[0], acc1 = (float)a01[1];
        float acc2 = (float)a23[0], acc3 = (float)a23[1];
        acc0 += __shfl_xor(acc0, 4, 16); acc0 += __shfl_xor(acc0, 8, 16);
        acc1 += __shfl_xor(acc1, 4, 16); acc1 += __shfl_xor(acc1, 8, 16);
        acc2 += __shfl_xor(acc2, 4, 16); acc2 += __shfl_xor(acc2, 8, 16);
        acc3 += __shfl_xor(acc3, 4, 16); acc3 += __shfl_xor(acc3, 8, 16);

        const float v0 = acc0 + b2s[4 * c];
        const float v1 = acc1 + b2s[4 * c + 1];
        const float v2 = acc2 + b2s[4 * c + 2];
        const float v3 = acc3 + b2s[4 * c + 3];
        float m = fmaxf(fmaxf(v0, v1), fmaxf(v2, v3));
        m = fmaxf(m, __shfl_xor(m, 1, 16));
        m = fmaxf(m, __shfl_xor(m, 2, 16));
        float sum = __expf(v0 - m) + __expf(v1 - m) + __expf(v2 - m) + __expf(v3 - m);
        sum += __shfl_xor(sum, 1, 16);
        sum += __shfl_xor(sum, 2, 16);
        if (p == 0) {
            const float lse = m + __logf(sum);
            float4 o = make_float4(v0 - lse, v1 - lse, v2 - lse, v3 - lse);
            *(float4*)&out[(size_t)node * F_OUT + 4 * c] = o;
        }
    }
}

// ---------------------------------------------------------------------------
extern "C" void kernel_launch(void* const* d_in, const int* in_sizes, int n_in,
                              void* d_out, int out_size, void* d_ws, size_t ws_size,
                              hipStream_t stream) {
    const float* x     = (const float*)d_in[0];
    const int*   esrc  = (const int*)  d_in[1];
    const int*   edst  = (const int*)  d_in[2];
    const float* evals = (const float*)d_in[3];
    const float* W1    = (const float*)d_in[4];
    const float* b1    = (const float*)d_in[5];
    const float* W2    = (const float*)d_in[6];
    const float* b2    = (const float*)d_in[7];
    float* out = (float*)d_out;

    // Workspace layout (~45.7 MB); all segments 16 B-aligned.
    char* ws = (char*)d_ws;
    _Float16* support1     = (_Float16*)(ws);              // 12,800,000 B
    _Float16* support2     = (_Float16*)(ws + 12800000);   //  3,200,000 B
    int2*     tmp          = (int2*)    (ws + 16000000);   // 14,413,824 B (NBKT*CAP*8)
    int2*     sorted_edges = (int2*)    (ws + 30413824);   // 14,413,824 B
    int2*     rowdeg       = (int2*)    (ws + 44827648);   //    800,000 B
    int*      bucketCursor = (int*)     (ws + 45627648);   //      1,568 B
    _Float16* W1h          = (_Float16*)(ws + 45629216);   //     32,768 B

    prep_kernel<<<64, 256, 0, stream>>>(W1, W1h, bucketCursor);
    gemm1_passA_kernel<<<GEMM1_BLOCKS + PA_BLOCKS, 256, 0, stream>>>(
        x, W1h, support1, esrc, edst, evals, bucketCursor, tmp);
    passB_kernel<<<NBKT, 1024, 0, stream>>>(tmp, bucketCursor, sorted_edges, rowdeg);
    spmm1_fused_kernel<<<N_NODES / 16, 256, 0, stream>>>(rowdeg, sorted_edges,
                                                         support1, b1, W2, support2);
    spmm2_fused_kernel<<<(N_NODES + 63) / 64, 256, 0, stream>>>(rowdeg, sorted_edges,
                                                                support2, b2, out);
}